// Round 3
// baseline (452.697 us; speedup 1.0000x reference)
//
#include <hip/hip_runtime.h>

// ForwardBackwardImputer == pure forward-fill (backward pass is provably a
// no-op: idx_rev[0]==L-1 always => cummax==L-1 => idx_bwd==0 everywhere, and
// on still_missing rows x_fwd==x[b,0,:]==x_bwd):
//   out[b,l,:] = x[b, F(b,l), :],  F(b,l) = cummax_{l'<=l}( valid(l') ? l' : 0 )
//   valid(l) <=> NOT all |x[b,l,d]| <= 1e-6
//
// 2-dispatch segment-local design:
//   k_main: one block per 128-row segment — validity, copy-through, and
//           in-segment fills (cache-hot). Publishes {first-valid, last-valid}.
//   k_fix : segments with missing head rows recompute the cross-segment
//           carry inline (<=15 L2-hot scalar loads) and fill the head.
//           ~90% of blocks early-return after one uniform load.

constexpr int Bn   = 256;
constexpr int Ln   = 2048;
constexpr int SEG  = 128;            // rows per block (64 KB of data)
constexpr int NSEG = Ln / SEG;       // 16 segments per batch
constexpr float A_TOL = 1e-6f;

// Native clang vector type: __builtin_nontemporal_store requires a vector of
// scalar types, not HIP's struct-based float4.
typedef float f4 __attribute__((ext_vector_type(4)));

// ---------------------------------------------------------------------------
// Main kernel: grid = Bn*NSEG blocks, 256 threads (32 lanes per row, 8 rows
// per iteration).
// ---------------------------------------------------------------------------
__global__ __launch_bounds__(256) void
k_main(const float* __restrict__ x, float* __restrict__ out,
       int* __restrict__ agg_first, int* __restrict__ agg_last) {
    const int sid    = blockIdx.x;
    const int b      = sid >> 4;               // NSEG = 16
    const int l0     = (sid & (NSEG - 1)) * SEG;
    const int tid    = threadIdx.x;
    const int lane32 = tid & 31;
    const int half   = (tid >> 5) & 1;         // which half of the wave64
    const int rgrp   = tid >> 5;               // row group 0..7

    __shared__ int sval[SEG];
    __shared__ unsigned long long sw[2];

    const f4* __restrict__ x4 = (const f4*)x;
    f4* __restrict__ o4       = (f4*)out;
    const size_t rowbase = (size_t)b * Ln + l0;   // global row index of row 0

    // ---- pass 1: load, validity, copy-through (nt store: out never re-read)
    #pragma unroll
    for (int it = 0; it < SEG / 8; ++it) {
        const int    r   = it * 8 + rgrp;
        const size_t off = (rowbase + r) * 32 + lane32;   // float4 units
        const f4 v = x4[off];
        const bool near0 = (__builtin_fabsf(v.x) <= A_TOL) &
                           (__builtin_fabsf(v.y) <= A_TOL) &
                           (__builtin_fabsf(v.z) <= A_TOL) &
                           (__builtin_fabsf(v.w) <= A_TOL);
        const unsigned long long bal = __ballot(near0);
        const unsigned mine = (unsigned)(bal >> (half * 32));
        const bool missing  = (mine == 0xffffffffu);   // all 128 features ~0
        if (!missing) __builtin_nontemporal_store(v, &o4[off]);
        if (lane32 == 0) sval[r] = missing ? 0 : 1;
    }
    __syncthreads();

    // ---- build 128-bit validity mask (wave 0 only) ----
    if (tid < 64) {
        const unsigned long long b0 = __ballot(sval[tid] != 0);
        const unsigned long long b1 = __ballot(sval[64 + tid] != 0);
        if (tid == 0) { sw[0] = b0; sw[1] = b1; }
    }
    __syncthreads();
    const unsigned long long m0 = sw[0], m1 = sw[1];

    // ---- pass 2: fill missing rows with in-segment predecessor ----
    #pragma unroll
    for (int it = 0; it < SEG / 8; ++it) {
        const int r = it * 8 + rgrp;
        if (sval[r]) continue;                 // valid: already written
        int F = -1;                            // last valid local idx <= r
        if (r >= 64) {
            unsigned long long m = m1 & ((r == 127) ? ~0ull
                                                    : ((1ull << (r - 63)) - 1ull));
            if (m)       F = 64 + 63 - __builtin_clzll(m);
            else if (m0) F = 63 - __builtin_clzll(m0);
        } else {
            unsigned long long m = m0 & ((r == 63) ? ~0ull
                                                   : ((1ull << (r + 1)) - 1ull));
            if (m) F = 63 - __builtin_clzll(m);
        }
        if (F < 0) continue;                   // head row -> k_fix
        const f4 s = x4[(rowbase + F) * 32 + lane32];   // L2/L3 hit
        __builtin_nontemporal_store(s, &o4[(rowbase + r) * 32 + lane32]);
    }

    // ---- per-segment aggregates ----
    if (tid == 0) {
        const int first = m0 ? __builtin_ctzll(m0)
                             : (m1 ? 64 + __builtin_ctzll(m1) : SEG);
        const int last  = m1 ? 127 - __builtin_clzll(m1)
                             : (m0 ? 63 - __builtin_clzll(m0) : -1);
        agg_first[sid] = first;                          // local idx of first valid (SEG if none)
        agg_last[sid]  = (last >= 0) ? (l0 + last) : -1; // batch-local l of last valid
    }
}

// ---------------------------------------------------------------------------
// Head fix-up with INLINE spine: segments whose leading rows are all-missing
// compute the cross-segment carry themselves (<=15 scalar loads over the
// 16 KB agg_last array, L2-hot) and fill rows [0, first) from the carry row.
// ---------------------------------------------------------------------------
__global__ __launch_bounds__(256) void
k_fix(const float* __restrict__ x, float* __restrict__ out,
      const int* __restrict__ agg_first, const int* __restrict__ agg_last) {
    const int sid   = blockIdx.x;
    const int first = agg_first[sid];          // uniform -> scalar load
    if (first == 0) return;                    // row 0 valid: nothing to do

    const int b = sid >> 4;
    const int s = sid & (NSEG - 1);
    const int l0 = s * SEG;

    // Inline exclusive running-max over preceding segments of this batch.
    int c = 0;                                 // F before the batch = 0
    for (int s2 = 0; s2 < s; ++s2)
        c = max(c, agg_last[(b << 4) + s2]);   // -1 sentinel keeps c

    const int lane32 = threadIdx.x & 31;
    const f4 v = ((const f4*)x)[((size_t)b * Ln + c) * 32 + lane32];
    f4* o4 = (f4*)out;
    for (int r = threadIdx.x >> 5; r < first; r += 8)
        __builtin_nontemporal_store(v, &o4[((size_t)b * Ln + l0 + r) * 32 + lane32]);
}

extern "C" void kernel_launch(void* const* d_in, const int* in_sizes, int n_in,
                              void* d_out, int out_size, void* d_ws, size_t ws_size,
                              hipStream_t stream) {
    const float* x = (const float*)d_in[0];
    float* out     = (float*)d_out;

    int* agg_first = (int*)d_ws;                   // Bn*NSEG = 4096 ints
    int* agg_last  = agg_first + Bn * NSEG;        // 4096 ints (32 KB total)

    const int nseg = Bn * NSEG;                    // 4096 blocks
    k_main<<<nseg, 256, 0, stream>>>(x, out, agg_first, agg_last);
    k_fix <<<nseg, 256, 0, stream>>>(x, out, agg_first, agg_last);
}